// Round 12
// baseline (264.268 us; speedup 1.0000x reference)
//
#include <hip/hip_runtime.h>
#include <math.h>
#include <float.h>

#define PSZ 256
#define NPATCH 127
#define L 16129            // 127*127
#define LPAD 16132         // B row stride, multiple of 4 -> aligned float4
#define KTOP 4
#define TMAIN 256
#define RPT 2              // rows per thread (64-VGPR budget is a hard platform limit)
#define ROWS_PER_BLOCK (TMAIN * RPT)   // 512
#define NROWBLK 32                     // 32*512 = 16384 >= L
#define NS 32
#define SEGLEN 508                     // multiple of 4; 32*508 = 16256 >= L
#define ROWPAD 16384
#define GRP 16                         // tournament group size (m's per group)

// ---- workspace layout (float elements) ----
static constexpr size_t OFF_REFG = 0;                          // [2][256][256]
static constexpr size_t OFF_XG   = OFF_REFG + 2 * PSZ * PSZ;
static constexpr size_t OFF_MUI  = OFF_XG   + 2 * PSZ * PSZ;   // [18]
static constexpr size_t OFF_MUR  = OFF_MUI  + 20;
static constexpr size_t OFF_A    = OFF_MUR  + 20;              // [2][L][9] input_norm
static constexpr size_t OFF_B    = OFF_A    + 290324;          // [2][9][LPAD] ref_norm (p-major, padded)
static constexpr size_t OFF_BT   = OFF_B    + 290376;          // [2][L][9] ref_norm (m-major)
static constexpr size_t OFF_IDX  = OFF_BT   + 290324;          // [2][L][4] final idx (int)
static constexpr size_t OFF_PV   = OFF_IDX  + 2 * L * 4;       // [2][NS][ROWPAD][4] group-max vals
static constexpr size_t OFF_PI   = OFF_PV   + (size_t)2 * NS * ROWPAD * 4;  // group bases (int)
// end ~= 9.2M floats (36.9 MB) <= 41.07 MB proven present.

// insert (rm, gb) into sorted-desc; strict > keeps earlier entry on ties
// (candidates arrive in ascending gb). Each group inserted exactly once.
__device__ __forceinline__ void insg(float rm, int gb,
    float& g0, float& g1, float& g2, float& g3,
    int& i0, int& i1, int& i2, int& i3) {
  bool c0 = rm > g0, c1 = rm > g1, c2 = rm > g2, c3 = rm > g3;
  g3 = c2 ? g2 : (c3 ? rm : g3);  i3 = c2 ? i2 : (c3 ? gb : i3);
  g2 = c1 ? g1 : (c2 ? rm : g2);  i2 = c1 ? i1 : (c2 ? gb : i2);
  g1 = c0 ? g0 : (c1 ? rm : g1);  i1 = c0 ? i0 : (c1 ? gb : i1);
  g0 = c0 ? rm : g0;              i0 = c0 ? gb : i0;
}

// composite-order insert: (v desc, m asc). NOT duplicate-safe -- callers must
// feed DISTINCT (v,m) candidates (k7's rescan ranges are disjoint: round-9 fix).
__device__ __forceinline__ void ins4c(float v, int m,
    float& v0, float& v1, float& v2, float& v3,
    int& x0, int& x1, int& x2, int& x3) {
  bool c0 = (v > v0) || (v == v0 && m < x0);
  bool c1 = (v > v1) || (v == v1 && m < x1);
  bool c2 = (v > v2) || (v == v2 && m < x2);
  bool c3 = (v > v3) || (v == v3 && m < x3);
  v3 = c2 ? v2 : (c3 ? v : v3);  x3 = c2 ? x2 : (c3 ? m : x3);
  v2 = c1 ? v1 : (c2 ? v : v2);  x2 = c1 ? x1 : (c2 ? m : x2);
  v1 = c0 ? v0 : (c1 ? v : v1);  x1 = c0 ? x0 : (c1 ? m : x1);
  v0 = c0 ? v : v0;              x0 = c0 ? m : x0;
}

// k12 (fused k1+k2): per 32x32 tile with 1-px halo in LDS:
// XG = 3x3 clipped-window max of channel-max(x) - channel-min(x);
// REFG = channel-mean(ref); copy x -> out[:, :3].
__global__ void k12_gray(const float* __restrict__ x, const float* __restrict__ ref,
                         float* __restrict__ ws, float* __restrict__ out) {
  __shared__ float sm[34][35];
  int tile = blockIdx.x & 63;        // 8x8 tiles of 32x32
  int b = blockIdx.x >> 6;
  int ty0 = (tile >> 3) << 5, tx0 = (tile & 7) << 5;
  const float* xb = x + (size_t)b * 3 * 65536;
  const float* rb = ref + (size_t)b * 3 * 65536;
  for (int hid = threadIdx.x; hid < 34 * 34; hid += 256) {
    int hy = hid / 34, hx = hid % 34;
    int gy = ty0 + hy - 1, gx = tx0 + hx - 1;
    float m = -FLT_MAX;
    if (gy >= 0 && gy < 256 && gx >= 0 && gx < 256) {
      int pix = gy * 256 + gx;
      m = fmaxf(fmaxf(xb[pix], xb[65536 + pix]), xb[131072 + pix]);
    }
    sm[hy][hx] = m;
  }
  __syncthreads();
  for (int iid = threadIdx.x; iid < 1024; iid += 256) {
    int iy = iid >> 5, ix = iid & 31;
    int gy = ty0 + iy, gx = tx0 + ix;
    int pix = gy * 256 + gx;
    float c0 = xb[pix], c1 = xb[65536 + pix], c2 = xb[131072 + pix];
    float cmin = fminf(fminf(c0, c1), c2);
    float mx = sm[iy][ix];
#pragma unroll
    for (int dy = 0; dy < 3; ++dy)
#pragma unroll
      for (int dx = 0; dx < 3; ++dx)
        mx = fmaxf(mx, sm[iy + dy][ix + dx]);
    size_t id = ((size_t)b << 16) + pix;
    ws[OFF_XG + id] = mx - cmin;
    ws[OFF_REFG + id] = (rb[pix] + rb[65536 + pix] + rb[131072 + pix]) / 3.0f;
    float* ob = out + (size_t)b * 7 * 65536 + pix;
    ob[0] = c0; ob[65536] = c1; ob[131072] = c2;
  }
}

// k4: per-(which,b,p) mean over L in f64. 36 blocks x 1024 threads.
__global__ void k4_mean(float* __restrict__ ws) {
  __shared__ double sm[1024];
  int which = blockIdx.x / 18;  // 0 = input(xg), 1 = ref(rg)
  int bp = blockIdx.x % 18;
  int b = bp / 9, p = bp % 9;
  int di = p / 3, dj = p % 3;
  const float* g = ws + (which ? OFF_REFG : OFF_XG) + ((size_t)b << 16);
  int t = threadIdx.x;
  double s = 0.0;
  int l0 = t * 16;
  if (l0 < L) {
    int l1 = l0 + 16 < L ? l0 + 16 : L;
    int i = l0 / NPATCH, j = l0 % NPATCH;
    for (int l = l0; l < l1; ++l) {
      s += (double)g[(2 * i + di) * PSZ + 2 * j + dj];
      if (++j == NPATCH) { j = 0; ++i; }
    }
  }
  sm[t] = s;
  __syncthreads();
  for (int st = 512; st > 0; st >>= 1) {
    if (t < st) sm[t] += sm[t + st];
    __syncthreads();
  }
  if (t == 0)
    ws[(which ? OFF_MUR : OFF_MUI) + bp] = (float)(sm[0] / (double)L);
}

// k5: per l compute patch values + uncentered norms, then
// A[b][l][9] = (ip-muI)/nI ; B[b][9][LPAD] and BT[b][l][9] = (rp-muR)/nR
__global__ void k5_norm(float* __restrict__ ws) {
  int id = blockIdx.x * 256 + threadIdx.x;
  if (id >= 2 * L) return;
  int b = id / L, l = id % L;
  int i = l / NPATCH, j = l % NPATCH;
  const float* xg = ws + OFF_XG + ((size_t)b << 16);
  const float* rg = ws + OFF_REFG + ((size_t)b << 16);
  float vi[9], vr[9];
  float si = 0.f, sr = 0.f;
#pragma unroll
  for (int p = 0; p < 9; ++p) {
    int di = p / 3, dj = p % 3;
    vi[p] = xg[(2 * i + di) * PSZ + 2 * j + dj];
    vr[p] = rg[(2 * i + di) * PSZ + 2 * j + dj];
    si += vi[p] * vi[p];
    sr += vr[p] * vr[p];
  }
  float ni = sqrtf(si), nr = sqrtf(sr);
#pragma unroll
  for (int p = 0; p < 9; ++p) {
    float mi = ws[OFF_MUI + b * 9 + p];
    float mr = ws[OFF_MUR + b * 9 + p];
    float bn = (vr[p] - mr) / nr;
    ws[OFF_A + ((size_t)b * L + l) * 9 + p] = (vi[p] - mi) / ni;
    ws[OFF_B + ((size_t)b * 9 + p) * LPAD + l] = bn;
    ws[OFF_BT + ((size_t)b * L + l) * 9 + p] = bn;
  }
}

// k6: fused ncc + per-(row,segment) top-4 GROUP-MAX tournament (16-m groups).
// NO LDS: B is read directly from global with WAVE-UNIFORM addresses through
// const __restrict__ pointers -> LLVM can promote to s_load (SMEM) + SGPR-
// operand v_fma, leaving the DS pipe idle (round 10 was DS-pipe-bound:
// 9.4M ds_read_b128 broadcasts ~ 8cyc = the 135-77us gap). B = 1.16 MB,
// L2-resident; block-level reuse now via K$/L2 instead of LDS.
// grid: 2 x 32(rowblk) x 32(seg) = 2048 blocks (8/CU by wave limit).
__global__ __launch_bounds__(TMAIN, 2) void k6_topk(
    const float* __restrict__ Bm, const float* __restrict__ Am,
    float* __restrict__ pv, int* __restrict__ pi) {
  int bid = blockIdx.x;
  int seg = bid % NS;
  int rowblk = (bid / NS) % NROWBLK;
  int b = bid / (NS * NROWBLK);
  int m0 = seg * SEGLEN;
  int mend = m0 + SEGLEN;
  if (mend > L) mend = L;
  int mlen = mend - m0;

  const float* Bseg = Bm + (size_t)b * 9 * LPAD + m0;  // uniform base, 16B-aligned rows

  int row0 = rowblk * ROWS_PER_BLOCK + threadIdx.x * RPT;
  int r0 = row0 < L - 1 ? row0 : L - 1;
  int r1 = row0 + 1 < L - 1 ? row0 + 1 : L - 1;
  float a0[9], a1[9];
  {
    const float* Ap0 = Am + ((size_t)b * L + r0) * 9;
    const float* Ap1 = Am + ((size_t)b * L + r1) * 9;
#pragma unroll
    for (int p = 0; p < 9; ++p) { a0[p] = Ap0[p]; a1[p] = Ap1[p]; }
  }

  float g00 = -FLT_MAX, g01 = g00, g02 = g00, g03 = g00;
  float g10 = g00, g11 = g00, g12 = g00, g13 = g00;
  int i00 = 0, i01 = 0, i02 = 0, i03 = 0;
  int i10 = 0, i11 = 0, i12 = 0, i13 = 0;

  int nfull = mlen >> 4;  // full groups of 16
  for (int g = 0; g < nfull; ++g) {
    int mm = g << 4;
    float rm0 = -FLT_MAX, rm1 = -FLT_MAX;
#pragma unroll
    for (int q = 0; q < 4; ++q) {
      float s00, s01, s02, s03, s10, s11, s12, s13;
#pragma unroll
      for (int p = 0; p < 9; ++p) {
        // wave-uniform, 16B-aligned -> s_load_dwordx4 candidate
        const float4 bq = *reinterpret_cast<const float4*>(Bseg + p * LPAD + mm + q * 4);
        if (p == 0) {
          s00 = a0[0] * bq.x; s01 = a0[0] * bq.y; s02 = a0[0] * bq.z; s03 = a0[0] * bq.w;
          s10 = a1[0] * bq.x; s11 = a1[0] * bq.y; s12 = a1[0] * bq.z; s13 = a1[0] * bq.w;
        } else {
          s00 = fmaf(a0[p], bq.x, s00); s01 = fmaf(a0[p], bq.y, s01);
          s02 = fmaf(a0[p], bq.z, s02); s03 = fmaf(a0[p], bq.w, s03);
          s10 = fmaf(a1[p], bq.x, s10); s11 = fmaf(a1[p], bq.y, s11);
          s12 = fmaf(a1[p], bq.z, s12); s13 = fmaf(a1[p], bq.w, s13);
        }
      }
      rm0 = fmaxf(rm0, fmaxf(fmaxf(s00, s01), fmaxf(s02, s03)));
      rm1 = fmaxf(rm1, fmaxf(fmaxf(s10, s11), fmaxf(s12, s13)));
    }
    int gb = m0 + mm;
    insg(rm0, gb, g00, g01, g02, g03, i00, i01, i02, i03);
    insg(rm1, gb, g10, g11, g12, g13, i10, i11, i12, i13);
  }
  // tail (< 16 m, in-segment only)
  int tb = nfull << 4;
  if (tb < mlen) {
    float rt0 = -FLT_MAX, rt1 = -FLT_MAX;
    for (int mm = tb; mm < mlen; ++mm) {
      float bb = Bseg[mm];
      float sv0 = a0[0] * bb, sv1 = a1[0] * bb;
#pragma unroll
      for (int p = 1; p < 9; ++p) {
        bb = Bseg[p * LPAD + mm];
        sv0 = fmaf(a0[p], bb, sv0); sv1 = fmaf(a1[p], bb, sv1);
      }
      rt0 = fmaxf(rt0, sv0); rt1 = fmaxf(rt1, sv1);
    }
    insg(rt0, m0 + tb, g00, g01, g02, g03, i00, i01, i02, i03);
    insg(rt1, m0 + tb, g10, g11, g12, g13, i10, i11, i12, i13);
  }

  if (row0 < L) {
    size_t base = (((size_t)b * NS + seg) * ROWPAD + row0) * 4;
    pv[base + 0] = g00; pv[base + 1] = g01; pv[base + 2] = g02; pv[base + 3] = g03;
    pi[base + 0] = i00; pi[base + 1] = i01; pi[base + 2] = i02; pi[base + 3] = i03;
  }
  if (row0 + 1 < L) {
    size_t base = (((size_t)b * NS + seg) * ROWPAD + row0 + 1) * 4;
    pv[base + 0] = g10; pv[base + 1] = g11; pv[base + 2] = g12; pv[base + 3] = g13;
    pi[base + 0] = i10; pi[base + 1] = i11; pi[base + 2] = i12; pi[base + 3] = i13;
  }
}

// k7: per row, merge 32 segs x 4 (group-max, base) -> top-4 groups by
// (max desc, base asc), then rescan those groups with ranges CLIPPED TO THE
// SEGMENT END (= exactly k6's group coverage; disjoint -> no duplicates).
__global__ void k7_merge(float* __restrict__ ws) {
  int id = blockIdx.x * 256 + threadIdx.x;
  if (id >= 2 * L) return;
  int b = id / L, row = id % L;
  const int* wsi_c = (const int*)ws;

  float v0 = -FLT_MAX, v1 = v0, v2 = v0, v3 = v0;
  int x0 = 0x7FFFFFFF, x1 = x0, x2 = x0, x3 = x0;
  for (int s = 0; s < NS; ++s) {
    size_t base = (((size_t)b * NS + s) * ROWPAD + row) * 4;
#pragma unroll
    for (int q = 0; q < 4; ++q) {
      float val = ws[OFF_PV + base + q];
      int gb = wsi_c[OFF_PI + base + q];
      ins4c(val, gb, v0, v1, v2, v3, x0, x1, x2, x3);
    }
  }

  float a[9];
  const float* Ap = ws + OFF_A + ((size_t)b * L + row) * 9;
#pragma unroll
  for (int p = 0; p < 9; ++p) a[p] = Ap[p];

  int gbs[4] = {x0, x1, x2, x3};
  float w0 = -FLT_MAX, w1 = w0, w2 = w0, w3 = w0;
  int y0 = 0x7FFFFFFF, y1 = y0, y2 = y0, y3 = y0;
#pragma unroll
  for (int slot = 0; slot < 4; ++slot) {
    int gb = gbs[slot];
    int se = (gb / SEGLEN + 1) * SEGLEN;   // owning segment's end
    int ge = gb + GRP;
    if (ge > se) ge = se;
    if (ge > L) ge = L;
    for (int mm = gb; mm < ge; ++mm) {
      const float* bt = ws + OFF_BT + ((size_t)b * L + mm) * 9;
      float s = a[0] * bt[0];
#pragma unroll
      for (int p = 1; p < 9; ++p) s = fmaf(a[p], bt[p], s);
      ins4c(s, mm, w0, w1, w2, w3, y0, y1, y2, y3);
    }
  }
  int* wsi = (int*)ws;
  size_t ib = OFF_IDX + (size_t)id * 4;
  wsi[ib] = y0; wsi[ib + 1] = y1; wsi[ib + 2] = y2; wsi[ib + 3] = y3;
}

// k8: fold (overlap-add) via per-output-pixel gather; reads ref_gray directly
__global__ void k8_fold(const float* __restrict__ ws, float* __restrict__ out) {
  int id = blockIdx.x * 256 + threadIdx.x;
  if (id >= 2 * KTOP * PSZ * PSZ) return;
  int b = id / (KTOP * PSZ * PSZ);
  int rem = id % (KTOP * PSZ * PSZ);
  int kk = rem >> 16;
  int pix = rem & 0xFFFF;
  int y = pix >> 8, xx = pix & 255;
  const int* wsi = (const int*)ws;
  const float* rg = ws + OFF_REFG + ((size_t)b << 16);
  float acc = 0.f;
  for (int di = 0; di < 3; ++di) {
    int yy = y - di;
    if (yy < 0 || (yy & 1) || (yy >> 1) >= NPATCH) continue;
    int i = yy >> 1;
    for (int dj = 0; dj < 3; ++dj) {
      int xc = xx - dj;
      if (xc < 0 || (xc & 1) || (xc >> 1) >= NPATCH) continue;
      int j = xc >> 1;
      int l = i * NPATCH + j;
      int m = wsi[OFF_IDX + ((size_t)b * L + l) * 4 + kk];
      int mi = m / NPATCH, mj = m % NPATCH;
      acc += rg[(2 * mi + di) * PSZ + 2 * mj + dj];
    }
  }
  out[(((size_t)b * 7 + 3 + kk) * PSZ + y) * PSZ + xx] = acc;
}

extern "C" void kernel_launch(void* const* d_in, const int* in_sizes, int n_in,
                              void* d_out, int out_size, void* d_ws, size_t ws_size,
                              hipStream_t stream) {
  const float* x = (const float*)d_in[0];
  const float* ref = (const float*)d_in[1];
  float* ws = (float*)d_ws;
  float* out = (float*)d_out;

  k12_gray<<<128, 256, 0, stream>>>(x, ref, ws, out);
  k4_mean<<<36, 1024, 0, stream>>>(ws);
  k5_norm<<<(2 * L + 255) / 256, 256, 0, stream>>>(ws);
  k6_topk<<<2 * NROWBLK * NS, TMAIN, 0, stream>>>(
      ws + OFF_B, ws + OFF_A, ws + OFF_PV, (int*)ws + OFF_PI);
  k7_merge<<<(2 * L + 255) / 256, 256, 0, stream>>>(ws);
  k8_fold<<<(2 * KTOP * PSZ * PSZ + 255) / 256, 256, 0, stream>>>(ws, out);
}

// Round 13
// 226.807 us; speedup vs baseline: 1.1652x; 1.1652x over previous
//
#include <hip/hip_runtime.h>
#include <math.h>
#include <float.h>

#define PSZ 256
#define NPATCH 127
#define L 16129            // 127*127
#define KTOP 4
#define TMAIN 256
#define RPT 2              // rows per thread (64-VGPR budget is a hard platform limit)
#define ROWS_PER_BLOCK (TMAIN * RPT)   // 512
#define NROWBLK 32                     // 32*512 = 16384 >= L
#define NS 32
#define SEGLEN 512                     // 32*512 = 16384 >= L; 31/32 segments have no tail
#define MSTRIDE 512                    // LDS stride (broadcast reads -> banks irrelevant)
#define ROWPAD 16384
#define GRP 16                         // tournament group size (m's per group)

// ---- workspace layout (float elements) ----
static constexpr size_t OFF_REFG = 0;                          // [2][256][256]
static constexpr size_t OFF_XG   = OFF_REFG + 2 * PSZ * PSZ;
static constexpr size_t OFF_MUI  = OFF_XG   + 2 * PSZ * PSZ;   // [18]
static constexpr size_t OFF_MUR  = OFF_MUI  + 20;
static constexpr size_t OFF_A    = OFF_MUR  + 20;              // [2][L][9] input_norm
static constexpr size_t OFF_B    = OFF_A    + 290324;          // [2][9][L] ref_norm (p-major)
static constexpr size_t OFF_BT   = OFF_B    + 290324;          // [2][L][9] ref_norm (m-major)
static constexpr size_t OFF_IDX  = OFF_BT   + 290324;          // [2][L][4] final idx (int)
static constexpr size_t OFF_PV   = OFF_IDX  + 2 * L * 4;       // [2][NS][ROWPAD][4] group-max vals
static constexpr size_t OFF_PI   = OFF_PV   + (size_t)2 * NS * ROWPAD * 4;  // group bases (int)
// end ~= 9.8M floats (39.1 MB) <= 41.07 MB proven present.

// insert (rm, gb) into sorted-desc; strict > keeps earlier entry on ties
// (candidates arrive in ascending gb). Each group inserted exactly once.
__device__ __forceinline__ void insg(float rm, int gb,
    float& g0, float& g1, float& g2, float& g3,
    int& i0, int& i1, int& i2, int& i3) {
  bool c0 = rm > g0, c1 = rm > g1, c2 = rm > g2, c3 = rm > g3;
  g3 = c2 ? g2 : (c3 ? rm : g3);  i3 = c2 ? i2 : (c3 ? gb : i3);
  g2 = c1 ? g1 : (c2 ? rm : g2);  i2 = c1 ? i1 : (c2 ? gb : i2);
  g1 = c0 ? g0 : (c1 ? rm : g1);  i1 = c0 ? i0 : (c1 ? gb : i1);
  g0 = c0 ? rm : g0;              i0 = c0 ? gb : i0;
}

// composite-order insert: (v desc, m asc). NOT duplicate-safe -- callers must
// feed DISTINCT (v,m) candidates (k7's rescan ranges are disjoint: round-9 fix).
__device__ __forceinline__ void ins4c(float v, int m,
    float& v0, float& v1, float& v2, float& v3,
    int& x0, int& x1, int& x2, int& x3) {
  bool c0 = (v > v0) || (v == v0 && m < x0);
  bool c1 = (v > v1) || (v == v1 && m < x1);
  bool c2 = (v > v2) || (v == v2 && m < x2);
  bool c3 = (v > v3) || (v == v3 && m < x3);
  v3 = c2 ? v2 : (c3 ? v : v3);  x3 = c2 ? x2 : (c3 ? m : x3);
  v2 = c1 ? v1 : (c2 ? v : v2);  x2 = c1 ? x1 : (c2 ? m : x2);
  v1 = c0 ? v0 : (c1 ? v : v1);  x1 = c0 ? x0 : (c1 ? m : x1);
  v0 = c0 ? v : v0;              x0 = c0 ? m : x0;
}

// k12 (fused k1+k2): per 32x32 tile with 1-px halo in LDS:
// XG = 3x3 clipped-window max of channel-max(x) - channel-min(x);
// REFG = channel-mean(ref); copy x -> out[:, :3].
__global__ void k12_gray(const float* __restrict__ x, const float* __restrict__ ref,
                         float* __restrict__ ws, float* __restrict__ out) {
  __shared__ float sm[34][35];
  int tile = blockIdx.x & 63;        // 8x8 tiles of 32x32
  int b = blockIdx.x >> 6;
  int ty0 = (tile >> 3) << 5, tx0 = (tile & 7) << 5;
  const float* xb = x + (size_t)b * 3 * 65536;
  const float* rb = ref + (size_t)b * 3 * 65536;
  for (int hid = threadIdx.x; hid < 34 * 34; hid += 256) {
    int hy = hid / 34, hx = hid % 34;
    int gy = ty0 + hy - 1, gx = tx0 + hx - 1;
    float m = -FLT_MAX;
    if (gy >= 0 && gy < 256 && gx >= 0 && gx < 256) {
      int pix = gy * 256 + gx;
      m = fmaxf(fmaxf(xb[pix], xb[65536 + pix]), xb[131072 + pix]);
    }
    sm[hy][hx] = m;
  }
  __syncthreads();
  for (int iid = threadIdx.x; iid < 1024; iid += 256) {
    int iy = iid >> 5, ix = iid & 31;
    int gy = ty0 + iy, gx = tx0 + ix;
    int pix = gy * 256 + gx;
    float c0 = xb[pix], c1 = xb[65536 + pix], c2 = xb[131072 + pix];
    float cmin = fminf(fminf(c0, c1), c2);
    float mx = sm[iy][ix];
#pragma unroll
    for (int dy = 0; dy < 3; ++dy)
#pragma unroll
      for (int dx = 0; dx < 3; ++dx)
        mx = fmaxf(mx, sm[iy + dy][ix + dx]);
    size_t id = ((size_t)b << 16) + pix;
    ws[OFF_XG + id] = mx - cmin;
    ws[OFF_REFG + id] = (rb[pix] + rb[65536 + pix] + rb[131072 + pix]) / 3.0f;
    float* ob = out + (size_t)b * 7 * 65536 + pix;
    ob[0] = c0; ob[65536] = c1; ob[131072] = c2;
  }
}

// k4: per-(which,b,p) mean over L in f64. 36 blocks x 1024 threads.
__global__ void k4_mean(float* __restrict__ ws) {
  __shared__ double sm[1024];
  int which = blockIdx.x / 18;  // 0 = input(xg), 1 = ref(rg)
  int bp = blockIdx.x % 18;
  int b = bp / 9, p = bp % 9;
  int di = p / 3, dj = p % 3;
  const float* g = ws + (which ? OFF_REFG : OFF_XG) + ((size_t)b << 16);
  int t = threadIdx.x;
  double s = 0.0;
  int l0 = t * 16;
  if (l0 < L) {
    int l1 = l0 + 16 < L ? l0 + 16 : L;
    int i = l0 / NPATCH, j = l0 % NPATCH;
    for (int l = l0; l < l1; ++l) {
      s += (double)g[(2 * i + di) * PSZ + 2 * j + dj];
      if (++j == NPATCH) { j = 0; ++i; }
    }
  }
  sm[t] = s;
  __syncthreads();
  for (int st = 512; st > 0; st >>= 1) {
    if (t < st) sm[t] += sm[t + st];
    __syncthreads();
  }
  if (t == 0)
    ws[(which ? OFF_MUR : OFF_MUI) + bp] = (float)(sm[0] / (double)L);
}

// k5: per l compute patch values + uncentered norms, then
// A[b][l][9] = (ip - muI)/nI ; B[b][9][L] and BT[b][l][9] = (rp - muR)/nR
__global__ void k5_norm(float* __restrict__ ws) {
  int id = blockIdx.x * 256 + threadIdx.x;
  if (id >= 2 * L) return;
  int b = id / L, l = id % L;
  int i = l / NPATCH, j = l % NPATCH;
  const float* xg = ws + OFF_XG + ((size_t)b << 16);
  const float* rg = ws + OFF_REFG + ((size_t)b << 16);
  float vi[9], vr[9];
  float si = 0.f, sr = 0.f;
#pragma unroll
  for (int p = 0; p < 9; ++p) {
    int di = p / 3, dj = p % 3;
    vi[p] = xg[(2 * i + di) * PSZ + 2 * j + dj];
    vr[p] = rg[(2 * i + di) * PSZ + 2 * j + dj];
    si += vi[p] * vi[p];
    sr += vr[p] * vr[p];
  }
  float ni = sqrtf(si), nr = sqrtf(sr);
#pragma unroll
  for (int p = 0; p < 9; ++p) {
    float mi = ws[OFF_MUI + b * 9 + p];
    float mr = ws[OFF_MUR + b * 9 + p];
    float bn = (vr[p] - mr) / nr;
    ws[OFF_A + ((size_t)b * L + l) * 9 + p] = (vi[p] - mi) / ni;
    ws[OFF_B + ((size_t)b * 9 + p) * L + l] = bn;
    ws[OFF_BT + ((size_t)b * L + l) * 9 + p] = bn;
  }
}

// k6: round-10 structure (proven best: LDS broadcast, RPT=2, GRP=16) with
// SEGLEN=512: segments 0..30 run exactly 32 full groups (no tail path),
// seg/segment arithmetic is shifts. SMEM (r12), RPT=4 (r11), pk-math (r8)
// all regressed -- 64-VGPR-fitting state + LDS broadcast is the optimum.
// grid: 2 x 32(rowblk) x 32(seg) = 2048 blocks (8/CU), 256 threads.
__global__ __launch_bounds__(TMAIN, 2) void k6_topk(float* __restrict__ ws) {
  __shared__ float lds[9 * MSTRIDE];  // 18432 B

  int bid = blockIdx.x;
  int seg = bid & (NS - 1);
  int rowblk = (bid >> 5) & (NROWBLK - 1);
  int b = bid >> 10;
  int m0 = seg << 9;
  int mend = m0 + SEGLEN;
  if (mend > L) mend = L;
  int mlen = mend - m0;

  const float* Bg = ws + OFF_B + (size_t)b * 9 * L + m0;
  for (int p = 0; p < 9; ++p)
    for (int mm = threadIdx.x; mm < mlen; mm += TMAIN)
      lds[p * MSTRIDE + mm] = Bg[(size_t)p * L + mm];
  __syncthreads();

  int row0 = rowblk * ROWS_PER_BLOCK + threadIdx.x * RPT;
  int r0 = row0 < L - 1 ? row0 : L - 1;
  int r1 = row0 + 1 < L - 1 ? row0 + 1 : L - 1;
  float a0[9], a1[9];
  {
    const float* Ap0 = ws + OFF_A + ((size_t)b * L + r0) * 9;
    const float* Ap1 = ws + OFF_A + ((size_t)b * L + r1) * 9;
#pragma unroll
    for (int p = 0; p < 9; ++p) { a0[p] = Ap0[p]; a1[p] = Ap1[p]; }
  }

  float g00 = -FLT_MAX, g01 = g00, g02 = g00, g03 = g00;
  float g10 = g00, g11 = g00, g12 = g00, g13 = g00;
  int i00 = 0, i01 = 0, i02 = 0, i03 = 0;
  int i10 = 0, i11 = 0, i12 = 0, i13 = 0;

  int nfull = mlen >> 4;  // full groups of 16 (== 32 for segs 0..30)
  for (int g = 0; g < nfull; ++g) {
    int mm = g << 4;
    float rm0 = -FLT_MAX, rm1 = -FLT_MAX;
#pragma unroll
    for (int q = 0; q < 4; ++q) {
      float s00, s01, s02, s03, s10, s11, s12, s13;
#pragma unroll
      for (int p = 0; p < 9; ++p) {
        const float4 bq = *reinterpret_cast<const float4*>(&lds[p * MSTRIDE + mm + q * 4]);
        if (p == 0) {
          s00 = a0[0] * bq.x; s01 = a0[0] * bq.y; s02 = a0[0] * bq.z; s03 = a0[0] * bq.w;
          s10 = a1[0] * bq.x; s11 = a1[0] * bq.y; s12 = a1[0] * bq.z; s13 = a1[0] * bq.w;
        } else {
          s00 = fmaf(a0[p], bq.x, s00); s01 = fmaf(a0[p], bq.y, s01);
          s02 = fmaf(a0[p], bq.z, s02); s03 = fmaf(a0[p], bq.w, s03);
          s10 = fmaf(a1[p], bq.x, s10); s11 = fmaf(a1[p], bq.y, s11);
          s12 = fmaf(a1[p], bq.z, s12); s13 = fmaf(a1[p], bq.w, s13);
        }
      }
      rm0 = fmaxf(rm0, fmaxf(fmaxf(s00, s01), fmaxf(s02, s03)));
      rm1 = fmaxf(rm1, fmaxf(fmaxf(s10, s11), fmaxf(s12, s13)));
    }
    int gb = m0 + mm;
    insg(rm0, gb, g00, g01, g02, g03, i00, i01, i02, i03);
    insg(rm1, gb, g10, g11, g12, g13, i10, i11, i12, i13);
  }
  // tail (< 16 m, only the last segment has one)
  int tb = nfull << 4;
  if (tb < mlen) {
    float rt0 = -FLT_MAX, rt1 = -FLT_MAX;
    for (int mm = tb; mm < mlen; ++mm) {
      float bb = lds[mm];
      float sv0 = a0[0] * bb, sv1 = a1[0] * bb;
#pragma unroll
      for (int p = 1; p < 9; ++p) {
        bb = lds[p * MSTRIDE + mm];
        sv0 = fmaf(a0[p], bb, sv0); sv1 = fmaf(a1[p], bb, sv1);
      }
      rt0 = fmaxf(rt0, sv0); rt1 = fmaxf(rt1, sv1);
    }
    insg(rt0, m0 + tb, g00, g01, g02, g03, i00, i01, i02, i03);
    insg(rt1, m0 + tb, g10, g11, g12, g13, i10, i11, i12, i13);
  }

  int* wsi = (int*)ws;
  if (row0 < L) {
    size_t base = (((size_t)b * NS + seg) * ROWPAD + row0) * 4;
    ws[OFF_PV + base + 0] = g00; ws[OFF_PV + base + 1] = g01;
    ws[OFF_PV + base + 2] = g02; ws[OFF_PV + base + 3] = g03;
    wsi[OFF_PI + base + 0] = i00; wsi[OFF_PI + base + 1] = i01;
    wsi[OFF_PI + base + 2] = i02; wsi[OFF_PI + base + 3] = i03;
  }
  if (row0 + 1 < L) {
    size_t base = (((size_t)b * NS + seg) * ROWPAD + row0 + 1) * 4;
    ws[OFF_PV + base + 0] = g10; ws[OFF_PV + base + 1] = g11;
    ws[OFF_PV + base + 2] = g12; ws[OFF_PV + base + 3] = g13;
    wsi[OFF_PI + base + 0] = i10; wsi[OFF_PI + base + 1] = i11;
    wsi[OFF_PI + base + 2] = i12; wsi[OFF_PI + base + 3] = i13;
  }
}

// k7: per row, merge 32 segs x 4 (group-max, base) -> top-4 groups by
// (max desc, base asc), then rescan those groups with ranges CLIPPED TO THE
// SEGMENT END (= exactly k6's group coverage; disjoint -> no duplicates).
__global__ void k7_merge(float* __restrict__ ws) {
  int id = blockIdx.x * 256 + threadIdx.x;
  if (id >= 2 * L) return;
  int b = id / L, row = id % L;
  const int* wsi_c = (const int*)ws;

  float v0 = -FLT_MAX, v1 = v0, v2 = v0, v3 = v0;
  int x0 = 0x7FFFFFFF, x1 = x0, x2 = x0, x3 = x0;
  for (int s = 0; s < NS; ++s) {
    size_t base = (((size_t)b * NS + s) * ROWPAD + row) * 4;
#pragma unroll
    for (int q = 0; q < 4; ++q) {
      float val = ws[OFF_PV + base + q];
      int gb = wsi_c[OFF_PI + base + q];
      ins4c(val, gb, v0, v1, v2, v3, x0, x1, x2, x3);
    }
  }

  float a[9];
  const float* Ap = ws + OFF_A + ((size_t)b * L + row) * 9;
#pragma unroll
  for (int p = 0; p < 9; ++p) a[p] = Ap[p];

  int gbs[4] = {x0, x1, x2, x3};
  float w0 = -FLT_MAX, w1 = w0, w2 = w0, w3 = w0;
  int y0 = 0x7FFFFFFF, y1 = y0, y2 = y0, y3 = y0;
#pragma unroll
  for (int slot = 0; slot < 4; ++slot) {
    int gb = gbs[slot];
    int se = ((gb >> 9) + 1) << 9;     // owning segment's end (SEGLEN = 512)
    int ge = gb + GRP;
    if (ge > se) ge = se;
    if (ge > L) ge = L;
    for (int mm = gb; mm < ge; ++mm) {
      const float* bt = ws + OFF_BT + ((size_t)b * L + mm) * 9;
      float s = a[0] * bt[0];
#pragma unroll
      for (int p = 1; p < 9; ++p) s = fmaf(a[p], bt[p], s);
      ins4c(s, mm, w0, w1, w2, w3, y0, y1, y2, y3);
    }
  }
  int* wsi = (int*)ws;
  size_t ib = OFF_IDX + (size_t)id * 4;
  wsi[ib] = y0; wsi[ib + 1] = y1; wsi[ib + 2] = y2; wsi[ib + 3] = y3;
}

// k8: fold (overlap-add) via per-output-pixel gather; reads ref_gray directly
__global__ void k8_fold(const float* __restrict__ ws, float* __restrict__ out) {
  int id = blockIdx.x * 256 + threadIdx.x;
  if (id >= 2 * KTOP * PSZ * PSZ) return;
  int b = id / (KTOP * PSZ * PSZ);
  int rem = id % (KTOP * PSZ * PSZ);
  int kk = rem >> 16;
  int pix = rem & 0xFFFF;
  int y = pix >> 8, xx = pix & 255;
  const int* wsi = (const int*)ws;
  const float* rg = ws + OFF_REFG + ((size_t)b << 16);
  float acc = 0.f;
  for (int di = 0; di < 3; ++di) {
    int yy = y - di;
    if (yy < 0 || (yy & 1) || (yy >> 1) >= NPATCH) continue;
    int i = yy >> 1;
    for (int dj = 0; dj < 3; ++dj) {
      int xc = xx - dj;
      if (xc < 0 || (xc & 1) || (xc >> 1) >= NPATCH) continue;
      int j = xc >> 1;
      int l = i * NPATCH + j;
      int m = wsi[OFF_IDX + ((size_t)b * L + l) * 4 + kk];
      int mi = m / NPATCH, mj = m % NPATCH;
      acc += rg[(2 * mi + di) * PSZ + 2 * mj + dj];
    }
  }
  out[(((size_t)b * 7 + 3 + kk) * PSZ + y) * PSZ + xx] = acc;
}

extern "C" void kernel_launch(void* const* d_in, const int* in_sizes, int n_in,
                              void* d_out, int out_size, void* d_ws, size_t ws_size,
                              hipStream_t stream) {
  const float* x = (const float*)d_in[0];
  const float* ref = (const float*)d_in[1];
  float* ws = (float*)d_ws;
  float* out = (float*)d_out;

  k12_gray<<<128, 256, 0, stream>>>(x, ref, ws, out);
  k4_mean<<<36, 1024, 0, stream>>>(ws);
  k5_norm<<<(2 * L + 255) / 256, 256, 0, stream>>>(ws);
  k6_topk<<<2 * NROWBLK * NS, TMAIN, 0, stream>>>(ws);
  k7_merge<<<(2 * L + 255) / 256, 256, 0, stream>>>(ws);
  k8_fold<<<(2 * KTOP * PSZ * PSZ + 255) / 256, 256, 0, stream>>>(ws, out);
}